// Round 2
// baseline (161687.463 us; speedup 1.0000x reference)
//
#include <hip/hip_runtime.h>
#include <cmath>

#define NN 10000
#define EE 200000
#define BB 64
#define NCK 50
#define NCAND 5
#define TOKS 38
#define TITLE 30
#define GDIM 300
#define HH 20
#define DHD 20
#define DD 400
#define PP 200

__device__ __forceinline__ float bf2f(unsigned short u) {
    return __uint_as_float(((unsigned int)u) << 16);
}
__device__ __forceinline__ unsigned short f2bf(float f) {
    unsigned int u = __float_as_uint(f);
    u += 0x7fffu + ((u >> 16) & 1u);
    return (unsigned short)(u >> 16);
}

// ---------------------------------------------------------------------------
// K1: fused news encoder. One block (256 thr) per news item.
// ---------------------------------------------------------------------------
struct __align__(16) NewsP1 {
    unsigned short embT[GDIM][40];   // [g][t] bf16 transposed; t in [30,40) zeroed
    unsigned short W3[30][64];       // per-head wq|wk|wv slice chunk, c in [60,64) zero
    float qkv[3][TITLE][DHD];
    float sc[TITLE][32];
};
struct __align__(16) NewsP2 {
    float wp_t[16][PP];
    float outf[16][36];              // transposed out tile [dd][t]
    float qpl[PP];
    float part[25][32];
};
struct __align__(16) NewsSmem {
    union { NewsP1 p1; NewsP2 p2; } u;  // 38880 B
    unsigned short outb[TITLE][408];     // 24480 B (bf16 attention output)
    int tok[32];
    float alpha[32];
};  // total ~63.6 KB

__global__ __launch_bounds__(256) void news_enc(
    const int* __restrict__ tokens, int tok_stride,
    const float* __restrict__ glove,
    const float* __restrict__ wq, const float* __restrict__ wk,
    const float* __restrict__ wv,
    const float* __restrict__ wp, const float* __restrict__ qp,
    float* __restrict__ out_enc)
{
    __shared__ NewsSmem sm;
    const int tid = threadIdx.x;
    const int item = blockIdx.x;

    if (tid < TITLE) sm.tok[tid] = tokens[(size_t)item * tok_stride + tid];
    __syncthreads();

    // gather glove rows -> embT (bf16, transposed)
    for (int i = tid; i < TITLE * 75; i += 256) {
        int t = i / 75, g4 = i % 75;
        const float4 v = *(const float4*)&glove[(size_t)sm.tok[t] * GDIM + g4 * 4];
        sm.u.p1.embT[g4*4+0][t] = f2bf(v.x);
        sm.u.p1.embT[g4*4+1][t] = f2bf(v.y);
        sm.u.p1.embT[g4*4+2][t] = f2bf(v.z);
        sm.u.p1.embT[g4*4+3][t] = f2bf(v.w);
    }
    for (int i = tid; i < GDIM * 10; i += 256) {   // zero t = 30..39
        int g = i / 10, t = TITLE + i % 10;
        sm.u.p1.embT[g][t] = 0;
    }

    const int col = tid & 63;          // 0..63 (cols 60..63 idle)
    const int tg  = tid >> 6;          // wave id 0..3
    const int t0  = tg * 8;
    const int nt  = (t0 + 8 <= TITLE) ? 8 : (TITLE - t0);   // 8,8,8,6

    for (int h = 0; h < HH; ++h) {
        float acc[8] = {0,0,0,0,0,0,0,0};
        for (int gc = 0; gc < 10; ++gc) {
            for (int i = tid; i < 30*64; i += 256) {
                int gg = i >> 6, c = i & 63;
                unsigned short val = 0;
                if (c < 60) {
                    int m = c / 20, cc = c % 20;
                    const float* W = (m == 0) ? wq : ((m == 1) ? wk : wv);
                    val = f2bf(W[(size_t)(gc*30+gg)*DD + h*DHD + cc]);
                }
                sm.u.p1.W3[gg][c] = val;
            }
            __syncthreads();
            for (int gg = 0; gg < 30; ++gg) {
                const uint4 pk = *(const uint4*)&sm.u.p1.embT[gc*30+gg][t0];
                float e0 = __uint_as_float(pk.x << 16);
                float e1 = __uint_as_float(pk.x & 0xffff0000u);
                float e2 = __uint_as_float(pk.y << 16);
                float e3 = __uint_as_float(pk.y & 0xffff0000u);
                float e4 = __uint_as_float(pk.z << 16);
                float e5 = __uint_as_float(pk.z & 0xffff0000u);
                float e6 = __uint_as_float(pk.w << 16);
                float e7 = __uint_as_float(pk.w & 0xffff0000u);
                float w = bf2f(sm.u.p1.W3[gg][col]);
                acc[0] += e0*w; acc[1] += e1*w; acc[2] += e2*w; acc[3] += e3*w;
                acc[4] += e4*w; acc[5] += e5*w; acc[6] += e6*w; acc[7] += e7*w;
            }
            __syncthreads();
        }
        if (col < 60) {
            int m = col / 20, cc = col % 20;
            for (int j = 0; j < nt; ++j) sm.u.p1.qkv[m][t0+j][cc] = acc[j];
        }
        __syncthreads();
        // scores = q k^T * 1/sqrt(20)
        for (int i = tid; i < TITLE*TITLE; i += 256) {
            int t = i / TITLE, k2 = i % TITLE;
            float s = 0.f;
            #pragma unroll
            for (int d4 = 0; d4 < 5; ++d4) {
                const float4 qa = *(const float4*)&sm.u.p1.qkv[0][t][d4*4];
                const float4 kb = *(const float4*)&sm.u.p1.qkv[1][k2][d4*4];
                s += qa.x*kb.x + qa.y*kb.y + qa.z*kb.z + qa.w*kb.w;
            }
            sm.u.p1.sc[t][k2] = s * 0.2236067977f;
        }
        __syncthreads();
        if (tid < TITLE) {
            float mx = -1e30f;
            for (int k2 = 0; k2 < TITLE; ++k2) mx = fmaxf(mx, sm.u.p1.sc[tid][k2]);
            float ssum = 0.f;
            for (int k2 = 0; k2 < TITLE; ++k2) {
                float e = __expf(sm.u.p1.sc[tid][k2] - mx);
                sm.u.p1.sc[tid][k2] = e; ssum += e;
            }
            float inv = 1.f / ssum;
            for (int k2 = 0; k2 < TITLE; ++k2) sm.u.p1.sc[tid][k2] *= inv;
        }
        __syncthreads();
        for (int i = tid; i < TITLE*DHD; i += 256) {
            int t = i / DHD, d = i % DHD;
            float o = 0.f;
            for (int k2 = 0; k2 < TITLE; ++k2)
                o += sm.u.p1.sc[t][k2] * sm.u.p1.qkv[2][k2][d];
            sm.outb[t][h*DHD + d] = f2bf(o);
        }
        __syncthreads();
    }

    // ---- token attention pooling ----
    for (int i = tid; i < PP; i += 256) sm.u.p2.qpl[i] = qp[i];
    float sreg[4][8];
    #pragma unroll
    for (int i = 0; i < 4; ++i)
        #pragma unroll
        for (int j = 0; j < 8; ++j) sreg[i][j] = 0.f;
    const int tb = tid & 7, pb = tid >> 3;   // valid for tid<200
    for (int dc = 0; dc < 25; ++dc) {
        for (int i = tid; i < 16*PP; i += 256) {
            int dd = i / PP, p = i % PP;
            sm.u.p2.wp_t[dd][p] = wp[(size_t)(dc*16+dd)*PP + p];
        }
        for (int i = tid; i < 16*36; i += 256) {
            int dd = i / 36, t = i % 36;
            sm.u.p2.outf[dd][t] = (t < TITLE) ? bf2f(sm.outb[t][dc*16+dd]) : 0.f;
        }
        __syncthreads();
        if (tid < 200) {
            for (int dd = 0; dd < 16; ++dd) {
                const float4 ev = *(const float4*)&sm.u.p2.outf[dd][tb*4];
                const float4 w0 = *(const float4*)&sm.u.p2.wp_t[dd][pb*8];
                const float4 w1 = *(const float4*)&sm.u.p2.wp_t[dd][pb*8+4];
                float evv[4] = {ev.x, ev.y, ev.z, ev.w};
                float wvv[8] = {w0.x,w0.y,w0.z,w0.w,w1.x,w1.y,w1.z,w1.w};
                #pragma unroll
                for (int i2 = 0; i2 < 4; ++i2)
                    #pragma unroll
                    for (int j = 0; j < 8; ++j) sreg[i2][j] += evv[i2]*wvv[j];
            }
        }
        __syncthreads();
    }
    if (tid < 200) {
        #pragma unroll
        for (int i2 = 0; i2 < 4; ++i2) {
            float part = 0.f;
            #pragma unroll
            for (int j = 0; j < 8; ++j)
                part += tanhf(sreg[i2][j]) * sm.u.p2.qpl[pb*8+j];
            sm.u.p2.part[pb][tb*4+i2] = part;
        }
    }
    __syncthreads();
    if (tid < TITLE) {
        float s = 0.f;
        for (int p2 = 0; p2 < 25; ++p2) s += sm.u.p2.part[p2][tid];
        sm.alpha[tid] = s;
    }
    __syncthreads();
    if (tid == 0) {
        float mx = -1e30f;
        for (int t = 0; t < TITLE; ++t) mx = fmaxf(mx, sm.alpha[t]);
        float ssum = 0.f;
        for (int t = 0; t < TITLE; ++t) { float e = __expf(sm.alpha[t]-mx); sm.alpha[t] = e; ssum += e; }
        float inv = 1.f/ssum;
        for (int t = 0; t < TITLE; ++t) sm.alpha[t] *= inv;
    }
    __syncthreads();
    for (int d = tid; d < DD; d += 256) {
        float a = 0.f;
        for (int t = 0; t < TITLE; ++t) a += sm.alpha[t] * bf2f(sm.outb[t][d]);
        out_enc[(size_t)item*DD + d] = a;
    }
}

// ---------------------------------------------------------------------------
// K2a: m = h @ W  ([N,400]@[400,400]); 8 rows per block
// ---------------------------------------------------------------------------
__global__ __launch_bounds__(256) void mm_nodes(
    const float* __restrict__ A, const float* __restrict__ W, float* __restrict__ Mo)
{
    __shared__ float a[8][DD];
    const int r0 = blockIdx.x * 8, tid = threadIdx.x;
    for (int i = tid; i < 8*DD; i += 256)
        a[i/DD][i%DD] = A[(size_t)(r0 + i/DD)*DD + i%DD];
    __syncthreads();
    for (int d = tid; d < DD; d += 256) {
        float acc[8] = {0,0,0,0,0,0,0,0};
        for (int k4 = 0; k4 < 100; ++k4) {
            float w0 = W[(size_t)(k4*4+0)*DD + d];
            float w1 = W[(size_t)(k4*4+1)*DD + d];
            float w2 = W[(size_t)(k4*4+2)*DD + d];
            float w3 = W[(size_t)(k4*4+3)*DD + d];
            #pragma unroll
            for (int r = 0; r < 8; ++r) {
                const float4 av = *(const float4*)&a[r][k4*4];
                acc[r] += av.x*w0 + av.y*w1 + av.z*w2 + av.w*w3;
            }
        }
        for (int r = 0; r < 8; ++r) Mo[(size_t)(r0+r)*DD + d] = acc[r];
    }
}

// ---------------------------------------------------------------------------
// CSR build: count -> exclusive scan -> cursor scatter (deterministic work,
// only 2*EE int atomics instead of 80M float atomics per layer)
// ---------------------------------------------------------------------------
__global__ __launch_bounds__(256) void count_edges(
    const int* __restrict__ ei, int* __restrict__ cnt)
{
    int e = blockIdx.x * 256 + threadIdx.x;
    if (e < EE) atomicAdd(&cnt[ei[EE + e]], 1);
}

__global__ __launch_bounds__(256) void build_offsets(
    const int* __restrict__ cnt, int* __restrict__ off, int* __restrict__ cursor)
{
    __shared__ int csum[256];
    const int tid = threadIdx.x;
    const int chunk = (NN + 255) / 256;   // 40
    int s = 0;
    for (int i = 0; i < chunk; ++i) {
        int idx = tid * chunk + i;
        if (idx < NN) s += cnt[idx];
    }
    csum[tid] = s;
    __syncthreads();
    if (tid == 0) {
        int run = 0;
        for (int i = 0; i < 256; ++i) { int c = csum[i]; csum[i] = run; run += c; }
    }
    __syncthreads();
    int run = csum[tid];
    for (int i = 0; i < chunk; ++i) {
        int idx = tid * chunk + i;
        if (idx < NN) {
            off[idx] = run; cursor[idx] = run;
            run += cnt[idx];
        }
    }
}

__global__ __launch_bounds__(256) void fill_csr(
    const int* __restrict__ ei, int* __restrict__ cursor, int* __restrict__ srclist)
{
    int e = blockIdx.x * 256 + threadIdx.x;
    if (e < EE) {
        int d = ei[EE + e];
        int pos = atomicAdd(&cursor[d], 1);
        srclist[pos] = ei[e];
    }
}

// ---------------------------------------------------------------------------
// K2b: agg[node] = sum over incoming edges of m[src]  (no float atomics)
// one block per node; coalesced loads of m rows
// ---------------------------------------------------------------------------
__global__ __launch_bounds__(256) void gather_agg(
    const float* __restrict__ m, const int* __restrict__ off,
    const int* __restrict__ cnt, const int* __restrict__ srclist,
    float* __restrict__ agg)
{
    __shared__ int sl[128];
    const int node = blockIdx.x, tid = threadIdx.x;
    const int o0 = off[node], deg = cnt[node];
    float acc0 = 0.f, acc1 = 0.f;
    const int d0 = tid, d1 = tid + 256;          // d1 valid if < 400
    for (int j0 = 0; j0 < deg; j0 += 128) {
        if (tid < 128 && j0 + tid < deg) sl[tid] = srclist[o0 + j0 + tid];
        __syncthreads();
        const int jn = (deg - j0 < 128) ? (deg - j0) : 128;
        for (int j = 0; j < jn; ++j) {
            const float* mr = &m[(size_t)sl[j] * DD];
            acc0 += mr[d0];
            if (d1 < DD) acc1 += mr[d1];
        }
        __syncthreads();
    }
    agg[(size_t)node * DD + d0] = acc0;
    if (d1 < DD) agg[(size_t)node * DD + d1] = acc1;
}

// ---------------------------------------------------------------------------
// K2c: fused GRU cell; 8 rows per block. Safe in-place (hin may == hout).
// ---------------------------------------------------------------------------
__global__ __launch_bounds__(256) void gru_step(
    const float* __restrict__ agg, const float* __restrict__ hin,
    const float* __restrict__ wih, const float* __restrict__ whh,
    const float* __restrict__ bih, const float* __restrict__ bhh,
    float* __restrict__ hout)
{
    __shared__ float al[8][DD], hl[8][DD];
    const int r0 = blockIdx.x * 8, tid = threadIdx.x;
    for (int i = tid; i < 8*DD; i += 256) {
        int r = i/DD, k = i%DD;
        al[r][k] = agg[(size_t)(r0+r)*DD + k];
        hl[r][k] = hin[(size_t)(r0+r)*DD + k];
    }
    __syncthreads();
    for (int d = tid; d < DD; d += 256) {
        float air[8]={0,0,0,0,0,0,0,0}, aiz[8]={0,0,0,0,0,0,0,0}, ain[8]={0,0,0,0,0,0,0,0};
        float ahr[8]={0,0,0,0,0,0,0,0}, ahz[8]={0,0,0,0,0,0,0,0}, ahn[8]={0,0,0,0,0,0,0,0};
        for (int k = 0; k < DD; ++k) {
            const float* wi = &wih[(size_t)k*1200 + d];
            float wir = wi[0], wiz = wi[400], win = wi[800];
            const float* wh = &whh[(size_t)k*1200 + d];
            float whr = wh[0], whz = wh[400], whn = wh[800];
            #pragma unroll
            for (int r = 0; r < 8; ++r) {
                float a = al[r][k], hh = hl[r][k];
                air[r] += a*wir; aiz[r] += a*wiz; ain[r] += a*win;
                ahr[r] += hh*whr; ahz[r] += hh*whz; ahn[r] += hh*whn;
            }
        }
        float bir = bih[d], biz = bih[d+400], bin = bih[d+800];
        float bhr = bhh[d], bhz = bhh[d+400], bhn = bhh[d+800];
        #pragma unroll
        for (int r = 0; r < 8; ++r) {
            float rg = 1.f/(1.f + __expf(-(air[r]+bir + ahr[r]+bhr)));
            float zg = 1.f/(1.f + __expf(-(aiz[r]+biz + ahz[r]+bhz)));
            float ng = tanhf(ain[r]+bin + rg*(ahn[r]+bhn));
            hout[(size_t)(r0+r)*DD + d] = (1.f-zg)*ng + zg*hl[r][d];
        }
    }
}

// ---------------------------------------------------------------------------
// K3a: clicked_total = concat(x_enc[midx], h[midx])*mask @ w_click + b_click
// ---------------------------------------------------------------------------
__global__ __launch_bounds__(256) void clicked_mm(
    const int* __restrict__ map, const float* __restrict__ xe,
    const float* __restrict__ hg, const float* __restrict__ wc,
    const float* __restrict__ bc, float* __restrict__ ct)
{
    __shared__ float a[8][2*DD];
    const int r0 = blockIdx.x * 8, tid = threadIdx.x;
    for (int i = tid; i < 8*2*DD; i += 256) {
        int r = i/(2*DD), k = i%(2*DD);
        int mi = map[r0 + r];
        float v = 0.f;
        if (mi >= 0) v = (k < DD) ? xe[(size_t)mi*DD + k] : hg[(size_t)mi*DD + (k-DD)];
        a[r][k] = v;
    }
    __syncthreads();
    for (int d = tid; d < DD; d += 256) {
        float acc[8] = {0,0,0,0,0,0,0,0};
        for (int k = 0; k < 2*DD; ++k) {
            float w = wc[(size_t)k*DD + d];
            #pragma unroll
            for (int r = 0; r < 8; ++r) acc[r] += a[r][k]*w;
        }
        float bb = bc[d];
        for (int r = 0; r < 8; ++r) ct[(size_t)(r0+r)*DD + d] = acc[r] + bb;
    }
}

// ---------------------------------------------------------------------------
// K3b: uq/uk/uv = ct @ u_wq/u_wk/u_wv
// ---------------------------------------------------------------------------
__global__ __launch_bounds__(256) void user_qkv(
    const float* __restrict__ ct,
    const float* __restrict__ wq, const float* __restrict__ wk, const float* __restrict__ wv,
    float* __restrict__ uq, float* __restrict__ uk, float* __restrict__ uv)
{
    __shared__ float a[8][DD];
    const int r0 = blockIdx.x * 8, tid = threadIdx.x;
    for (int i = tid; i < 8*DD; i += 256)
        a[i/DD][i%DD] = ct[(size_t)(r0 + i/DD)*DD + i%DD];
    __syncthreads();
    for (int d = tid; d < DD; d += 256) {
        float aq[8]={0,0,0,0,0,0,0,0}, ak[8]={0,0,0,0,0,0,0,0}, av[8]={0,0,0,0,0,0,0,0};
        for (int k = 0; k < DD; ++k) {
            float wq_ = wq[(size_t)k*DD + d];
            float wk_ = wk[(size_t)k*DD + d];
            float wv_ = wv[(size_t)k*DD + d];
            #pragma unroll
            for (int r = 0; r < 8; ++r) {
                float x = a[r][k];
                aq[r] += x*wq_; ak[r] += x*wk_; av[r] += x*wv_;
            }
        }
        for (int r = 0; r < 8; ++r) {
            uq[(size_t)(r0+r)*DD + d] = aq[r];
            uk[(size_t)(r0+r)*DD + d] = ak[r];
            uv[(size_t)(r0+r)*DD + d] = av[r];
        }
    }
}

// ---------------------------------------------------------------------------
// K3c: masked MHSA per (batch, head); block = 64 threads
// ---------------------------------------------------------------------------
__global__ __launch_bounds__(64) void user_attn(
    const float* __restrict__ uq, const float* __restrict__ uk,
    const float* __restrict__ uv, const int* __restrict__ map,
    float* __restrict__ uo)
{
    const int b = blockIdx.x / HH, h = blockIdx.x % HH, tid = threadIdx.x;
    __shared__ float q[NCK][DHD], k[NCK][DHD], v[NCK][DHD];
    __shared__ float sc[NCK][NCK+2];
    __shared__ float biasl[NCK];
    for (int i = tid; i < NCK*DHD; i += 64) {
        int c = i/DHD, d = i%DHD;
        size_t base = ((size_t)b*NCK + c)*DD + h*DHD + d;
        q[c][d] = uq[base]; k[c][d] = uk[base]; v[c][d] = uv[base];
    }
    for (int i = tid; i < NCK; i += 64)
        biasl[i] = (map[b*NCK + i] >= 0) ? 0.f : -1e9f;
    __syncthreads();
    for (int i = tid; i < NCK*NCK; i += 64) {
        int t = i/NCK, k2 = i%NCK;
        float s = 0.f;
        #pragma unroll
        for (int d4 = 0; d4 < 5; ++d4) {
            const float4 qa = *(const float4*)&q[t][d4*4];
            const float4 kb = *(const float4*)&k[k2][d4*4];
            s += qa.x*kb.x + qa.y*kb.y + qa.z*kb.z + qa.w*kb.w;
        }
        sc[t][k2] = s * 0.2236067977f + biasl[k2];
    }
    __syncthreads();
    if (tid < NCK) {
        float mx = -1e30f;
        for (int k2 = 0; k2 < NCK; ++k2) mx = fmaxf(mx, sc[tid][k2]);
        float ssum = 0.f;
        for (int k2 = 0; k2 < NCK; ++k2) { float e = __expf(sc[tid][k2]-mx); sc[tid][k2] = e; ssum += e; }
        float inv = 1.f/ssum;
        for (int k2 = 0; k2 < NCK; ++k2) sc[tid][k2] *= inv;
    }
    __syncthreads();
    for (int i = tid; i < NCK*DHD; i += 64) {
        int t = i/DHD, d = i%DHD;
        float o = 0.f;
        for (int k2 = 0; k2 < NCK; ++k2) o += sc[t][k2]*v[k2][d];
        uo[((size_t)b*NCK + t)*DD + h*DHD + d] = o;
    }
}

// ---------------------------------------------------------------------------
// K3d: masked attention pooling -> user_emb[b][400]; block per batch
// ---------------------------------------------------------------------------
__global__ __launch_bounds__(256) void user_pool(
    const float* __restrict__ uo, const int* __restrict__ map,
    const float* __restrict__ uwp, const float* __restrict__ uqp,
    float* __restrict__ user_emb)
{
    const int b = blockIdx.x, tid = threadIdx.x;
    __shared__ float alpha[64];
    __shared__ float red[256];
    for (int t = 0; t < NCK; ++t) {
        float partial = 0.f;
        const float* ur = uo + ((size_t)b*NCK + t)*DD;
        for (int p = tid; p < PP; p += 256) {
            float s = 0.f;
            for (int d = 0; d < DD; ++d) s += ur[d] * uwp[(size_t)d*PP + p];
            partial += tanhf(s) * uqp[p];
        }
        red[tid] = partial; __syncthreads();
        for (int st = 128; st > 0; st >>= 1) {
            if (tid < st) red[tid] += red[tid+st];
            __syncthreads();
        }
        if (tid == 0)
            alpha[t] = red[0] + ((map[b*NCK + t] >= 0) ? 0.f : -1e9f);
        __syncthreads();
    }
    if (tid == 0) {
        float mx = -1e30f;
        for (int t = 0; t < NCK; ++t) mx = fmaxf(mx, alpha[t]);
        float ssum = 0.f;
        for (int t = 0; t < NCK; ++t) { float e = __expf(alpha[t]-mx); alpha[t] = e; ssum += e; }
        float inv = 1.f/ssum;
        for (int t = 0; t < NCK; ++t) alpha[t] *= inv;
    }
    __syncthreads();
    for (int d = tid; d < DD; d += 256) {
        float acc = 0.f;
        for (int t = 0; t < NCK; ++t) acc += alpha[t] * uo[((size_t)b*NCK + t)*DD + d];
        user_emb[(size_t)b*DD + d] = acc;
    }
}

// ---------------------------------------------------------------------------
// K5: candidate scoring + NCE loss; single block
// ---------------------------------------------------------------------------
__global__ __launch_bounds__(256) void score_loss(
    const float* __restrict__ cr, const float* __restrict__ cf,
    const float* __restrict__ ue, const int* __restrict__ label,
    float* __restrict__ dout)
{
    __shared__ float sr[BB][NCAND], sf[BB][NCAND], red[BB];
    const int tid = threadIdx.x;
    for (int i = tid; i < 2*BB*NCAND; i += 256) {
        int which = i / (BB*NCAND);
        int r = i % (BB*NCAND);
        int b = r / NCAND, c = r % NCAND;
        const float* ce = (which ? cf : cr) + (size_t)r*DD;
        const float* u = ue + (size_t)b*DD;
        float s = 0.f;
        for (int d = 0; d < DD; ++d) s += ce[d]*u[d];
        if (which) sf[b][c] = s; else sr[b][c] = s;
        dout[1 + i] = s;
    }
    __syncthreads();
    if (tid < BB) {
        int b = tid;
        float mr = -1e30f, mf = -1e30f;
        for (int c = 0; c < NCAND; ++c) { mr = fmaxf(mr, sr[b][c]); mf = fmaxf(mf, sf[b][c]); }
        float er = 0.f, ef = 0.f;
        for (int c = 0; c < NCAND; ++c) { er += expf(sr[b][c]-mr); ef += expf(sf[b][c]-mf); }
        float lser = logf(er)+mr, lsef = logf(ef)+mf;
        int lab = label[b]; lab = lab < 0 ? 0 : (lab > NCAND-1 ? NCAND-1 : lab);
        float crb = lser - sr[b][lab];
        float cfb = 0.f;
        for (int c = 0; c < NCAND; ++c) cfb += (lsef - sf[b][c]);
        red[tid] = crb + 0.5f * (cfb / (float)NCAND);
    }
    __syncthreads();
    if (tid == 0) {
        float L = 0.f;
        for (int b = 0; b < BB; ++b) L += red[b];
        dout[0] = L / (float)BB;
    }
}

// ---------------------------------------------------------------------------
extern "C" void kernel_launch(void* const* d_in, const int* in_sizes, int n_in,
                              void* d_out, int out_size, void* d_ws, size_t ws_size,
                              hipStream_t stream) {
    (void)in_sizes; (void)n_in; (void)out_size; (void)ws_size;
    const int*   sub_x  = (const int*)d_in[0];
    const int*   edge   = (const int*)d_in[1];
    const int*   mapi   = (const int*)d_in[2];
    const int*   cand   = (const int*)d_in[3];
    const int*   fcand  = (const int*)d_in[4];
    const int*   label  = (const int*)d_in[5];
    const float* glove  = (const float*)d_in[6];
    const float* nwq    = (const float*)d_in[7];
    const float* nwk    = (const float*)d_in[8];
    const float* nwv    = (const float*)d_in[9];
    const float* nwp    = (const float*)d_in[10];
    const float* nqp    = (const float*)d_in[11];
    const float* ggc    = (const float*)d_in[12];
    const float* wih    = (const float*)d_in[13];
    const float* whh    = (const float*)d_in[14];
    const float* bih    = (const float*)d_in[15];
    const float* bhh    = (const float*)d_in[16];
    const float* wclick = (const float*)d_in[17];
    const float* bclick = (const float*)d_in[18];
    const float* uwq    = (const float*)d_in[19];
    const float* uwk    = (const float*)d_in[20];
    const float* uwv    = (const float*)d_in[21];
    const float* uwp    = (const float*)d_in[22];
    const float* uqp    = (const float*)d_in[23];

    // workspace layout (floats); ws_size = 256 MB
    float* ws     = (float*)d_ws;
    float* x_enc  = ws;                       // 4,000,000 f
    float* hbuf   = ws + 4000000;             // 4,000,000 f
    float* region = ws + 8000000;             // 8,000,000 f shared region
    float* mbuf   = region;                   // GGC: m
    float* aggbuf = region + 4000000;         // GGC: agg
    // after GGC, region reused:
    float* ct   = region;                     // 1,280,000
    float* uq   = region + 1280000;
    float* uk   = region + 2560000;
    float* uv   = region + 3840000;
    float* uo   = region + 5120000;           // 1,280,000
    float* user = region + 6400000;           // 25,600
    float* crnc = region + 6425600;           // 128,000
    float* cfnc = region + 6553600;           // 128,000
    // int area at byte offset 64 MB
    int* ibase   = (int*)((char*)d_ws + (size_t)64*1024*1024);
    int* cnt     = ibase;                     // 10,000
    int* off     = ibase + 10000;             // 10,000
    int* cursor  = ibase + 20000;             // 10,000
    int* srclist = ibase + 30000;             // 200,000

    // 1) encode all nodes
    news_enc<<<NN, 256, 0, stream>>>(sub_x, TOKS, glove, nwq, nwk, nwv, nwp, nqp, x_enc);

    // 1b) build CSR-by-destination once (reused by all 3 GGC layers)
    hipMemsetAsync(cnt, 0, NN*sizeof(int), stream);
    count_edges<<<(EE+255)/256, 256, 0, stream>>>(edge, cnt);
    build_offsets<<<1, 256, 0, stream>>>(cnt, off, cursor);
    fill_csr<<<(EE+255)/256, 256, 0, stream>>>(edge, cursor, srclist);

    // 2) GatedGraphConv x3 (gather instead of atomic scatter)
    const float* hin = x_enc;
    for (int l = 0; l < 3; ++l) {
        mm_nodes<<<NN/8, 256, 0, stream>>>(hin, ggc + (size_t)l*DD*DD, mbuf);
        gather_agg<<<NN, 256, 0, stream>>>(mbuf, off, cnt, srclist, aggbuf);
        gru_step<<<NN/8, 256, 0, stream>>>(aggbuf, hin, wih, whh, bih, bhh, hbuf);
        hin = hbuf;
    }

    // 3) click + user encoder
    clicked_mm<<<(BB*NCK)/8, 256, 0, stream>>>(mapi, x_enc, hbuf, wclick, bclick, ct);
    user_qkv<<<(BB*NCK)/8, 256, 0, stream>>>(ct, uwq, uwk, uwv, uq, uk, uv);
    user_attn<<<BB*HH, 64, 0, stream>>>(uq, uk, uv, mapi, uo);
    user_pool<<<BB, 256, 0, stream>>>(uo, mapi, uwp, uqp, user);

    // 4) candidates
    news_enc<<<BB*NCAND, 256, 0, stream>>>(cand,  TOKS, glove, nwq, nwk, nwv, nwp, nqp, crnc);
    news_enc<<<BB*NCAND, 256, 0, stream>>>(fcand, TOKS, glove, nwq, nwk, nwv, nwp, nqp, cfnc);

    // 5) scores + loss
    score_loss<<<1, 256, 0, stream>>>(crnc, cfnc, user, label, (float*)d_out);
}